// Round 1
// baseline (114.730 us; speedup 1.0000x reference)
//
#include <hip/hip_runtime.h>

#define S_LEN 4096
#define DM    1024
#define NH    8
#define NKV   2
#define HDIM  128
#define WINSZ 256

typedef unsigned short u16;
typedef float f32x4 __attribute__((ext_vector_type(4)));
typedef short bf16x8 __attribute__((ext_vector_type(8)));

// ---------- workspace layout (bytes) ----------
static const size_t OFF_XB   = 0;          // x bf16 [4096][1024]            8388608
static const size_t OFF_WQKV = 8388608;    // Wq|Wk|Wv bf16 [1536][1024]     3145728
static const size_t OFF_WO   = 11534336;   // Wo bf16 [1024][1024]           2097152
static const size_t OFF_QH   = 13631488;   // q bf16 [8][4096][128]          8388608
static const size_t OFF_KH   = 22020096;   // k bf16 [2][4096][128]          2097152
static const size_t OFF_VT   = 24117248;   // v^T bf16 [2][128][4096]        2097152
static const size_t OFF_OB   = 26214400;   // attn out bf16 [4096][1024]     8388608
// total 34603008 bytes

__device__ __forceinline__ u16 f2bf(float f) {
  union { float f; unsigned int u; } v; v.f = f;
  unsigned int u = v.u;
  u += 0x7fffu + ((u >> 16) & 1u);   // RNE
  return (u16)(u >> 16);
}

__device__ __forceinline__ void gload_lds16(const u16* g, u16* l) {
  __builtin_amdgcn_global_load_lds((const __attribute__((address_space(1))) void*)g,
                                   (__attribute__((address_space(3))) void*)l, 16, 0, 0);
}

// ---------------- prep: f32 -> bf16 conversions ----------------
__global__ __launch_bounds__(256) void prep_kernel(
    const float* __restrict__ x,  const float* __restrict__ wq,
    const float* __restrict__ wk, const float* __restrict__ wv,
    const float* __restrict__ wo,
    u16* __restrict__ xb, u16* __restrict__ wqkvb, u16* __restrict__ wob) {
  int i = blockIdx.x * 256 + threadIdx.x;       // one float4 per thread
  const float* src; u16* dst;
  if (i < 1048576)      { src = x  + (size_t)i * 4;               dst = xb + (size_t)i * 4; }
  else if (i < 1310720) { int j = i - 1048576; src = wq + (size_t)j*4; dst = wqkvb + (size_t)j*4; }
  else if (i < 1376256) { int j = i - 1310720; src = wk + (size_t)j*4; dst = wqkvb + 1048576 + (size_t)j*4; }
  else if (i < 1441792) { int j = i - 1376256; src = wv + (size_t)j*4; dst = wqkvb + 1310720 + (size_t)j*4; }
  else                  { int j = i - 1441792; src = wo + (size_t)j*4; dst = wob + (size_t)j*4; }
  float4 v = *(const float4*)src;
  ushort4 o;
  o.x = f2bf(v.x); o.y = f2bf(v.y); o.z = f2bf(v.z); o.w = f2bf(v.w);
  *(ushort4*)dst = o;
}

// ---------------- GEMM: C[m][n] = sum_k A[m][k]*B[n][k]  (both K-major) ----------------
// 128x128 tile, BK=64, 4 waves (each 64x64 = 4x4 16x16x32 frags), global_load_lds staging.
// EPI 0: scatter to qh/kh/vt (bf16, +bias). EPI 1: f32 out (+bias).
template<int EPI>
__global__ __launch_bounds__(256) void gemm_bt(
    const u16* __restrict__ A, const u16* __restrict__ B,
    const float* __restrict__ b0, const float* __restrict__ b1, const float* __restrict__ b2,
    u16* __restrict__ qh, u16* __restrict__ kh, u16* __restrict__ vt,
    float* __restrict__ outf) {
  __shared__ __align__(16) u16 As[128 * 64];
  __shared__ __align__(16) u16 Bs[128 * 64];
  const int tid = threadIdx.x;
  const int w = tid >> 6, l = tid & 63;
  const int lo16 = l & 15, hi4 = l >> 4;
  const int m0 = blockIdx.x * 128;
  const int n0 = blockIdx.y * 128;
  const int wm = w >> 1, wn = w & 1;
  const int K = 1024;

  f32x4 acc[4][4] = {};

  const int lr = l >> 3;         // row within 8-row chunk
  const int lc = (l & 7) * 8;    // elem col within 64-wide row

  for (int kt = 0; kt < K; kt += 64) {
    #pragma unroll
    for (int it = 0; it < 4; ++it) {
      int c = w * 4 + it;                       // chunk 0..15 (8 rows each)
      int row = c * 8 + lr;
      gload_lds16(A + (size_t)(m0 + row) * K + kt + lc, (u16*)((char*)As + c * 1024));
      gload_lds16(B + (size_t)(n0 + row) * K + kt + lc, (u16*)((char*)Bs + c * 1024));
    }
    __syncthreads();
    #pragma unroll
    for (int kk = 0; kk < 2; ++kk) {
      bf16x8 af[4], bfr[4];
      const int colb = (kk * 32 + hi4 * 8) * 2;   // byte offset in 128B row
      #pragma unroll
      for (int f = 0; f < 4; ++f) {
        af[f]  = *(const bf16x8*)((const char*)As + (wm * 64 + f * 16 + lo16) * 128 + colb);
        bfr[f] = *(const bf16x8*)((const char*)Bs + (wn * 64 + f * 16 + lo16) * 128 + colb);
      }
      #pragma unroll
      for (int fm = 0; fm < 4; ++fm)
        #pragma unroll
        for (int fn = 0; fn < 4; ++fn)
          acc[fm][fn] = __builtin_amdgcn_mfma_f32_16x16x32_bf16(af[fm], bfr[fn], acc[fm][fn], 0, 0, 0);
    }
    __syncthreads();
  }

  // epilogue: C row = m0+wm*64+fm*16+hi4*4+j ; col = n0+wn*64+fn*16+lo16
  #pragma unroll
  for (int fm = 0; fm < 4; ++fm) {
    #pragma unroll
    for (int fn = 0; fn < 4; ++fn) {
      f32x4 c = acc[fm][fn];
      const int col  = n0 + wn * 64 + fn * 16 + lo16;
      const int rowb = m0 + wm * 64 + fm * 16 + hi4 * 4;
      if (EPI == 0) {
        float bias = (col < 1024) ? b0[col] : (col < 1280 ? b1[col - 1024] : b2[col - 1280]);
        #pragma unroll
        for (int j = 0; j < 4; ++j) {
          int m = rowb + j;
          u16 hb = f2bf(c[j] + bias);
          if (col < 1024) {
            qh[((size_t)(col >> 7) * S_LEN + m) * HDIM + (col & 127)] = hb;
          } else if (col < 1280) {
            int cc = col - 1024;
            kh[((size_t)(cc >> 7) * S_LEN + m) * HDIM + (cc & 127)] = hb;
          } else {
            int cc = col - 1280;
            vt[((size_t)(cc >> 7) * HDIM + (cc & 127)) * S_LEN + m] = hb;
          }
        }
      } else {
        float bias = b0[col];
        #pragma unroll
        for (int j = 0; j < 4; ++j)
          outf[(size_t)(rowb + j) * DM + col] = c[j] + bias;
      }
    }
  }
}

// ---------------- flash attention with sink + sliding window ----------------
// grid (S/64, H), 256 thr. Wave w: q rows qt*64+w*16 .. +15.
__global__ __launch_bounds__(256) void attn_kernel(
    const u16* __restrict__ qh, const u16* __restrict__ kh,
    const u16* __restrict__ vt, const float* __restrict__ sb_ptr,
    u16* __restrict__ ob) {
  const int qt = blockIdx.x;
  const int h  = blockIdx.y;
  const int g  = h >> 2;                 // H/KV = 4
  const int tid = threadIdx.x;
  const int w = tid >> 6, l = tid & 63;
  const int lo16 = l & 15, hi4 = l >> 4;
  const int r0 = qt * 64 + w * 16;
  const float sb = *sb_ptr;
  const float scale = 0.08838834764831845f;   // 1/sqrt(128)

  __shared__ __align__(16) u16 p_lds[4][16 * 64];

  // Q fragments (reused across key tiles)
  bf16x8 aq[4];
  {
    const u16* qbase = qh + ((size_t)h * S_LEN + r0 + lo16) * HDIM + hi4 * 8;
    #pragma unroll
    for (int kk = 0; kk < 4; ++kk) aq[kk] = *(const bf16x8*)(qbase + kk * 32);
  }

  float m_run[4], l_run[4];
  #pragma unroll
  for (int j = 0; j < 4; ++j) { m_run[j] = sb; l_run[j] = 0.f; }
  f32x4 acc_o[8] = {};

  int lo = qt * 64 - (WINSZ - 1); if (lo < 0) lo = 0;
  const int jt0 = lo >> 6;
  for (int jt = jt0; jt <= qt; ++jt) {
    // ---- QK^T ----
    f32x4 sc[4] = {};
    #pragma unroll
    for (int jn = 0; jn < 4; ++jn) {
      const u16* kbase = kh + ((size_t)g * S_LEN + jt * 64 + jn * 16 + lo16) * HDIM + hi4 * 8;
      #pragma unroll
      for (int kk = 0; kk < 4; ++kk) {
        bf16x8 bk = *(const bf16x8*)(kbase + kk * 32);
        sc[jn] = __builtin_amdgcn_mfma_f32_16x16x32_bf16(aq[kk], bk, sc[jn], 0, 0, 0);
      }
    }
    // ---- mask + scale + row max ----
    float sv[4][4], pmax[4];
    #pragma unroll
    for (int j = 0; j < 4; ++j) pmax[j] = -1e30f;
    #pragma unroll
    for (int jn = 0; jn < 4; ++jn) {
      int jg = jt * 64 + jn * 16 + lo16;
      #pragma unroll
      for (int j = 0; j < 4; ++j) {
        int ig = r0 + hi4 * 4 + j;
        float s = sc[jn][j] * scale;
        bool valid = (jg <= ig) && (jg > ig - WINSZ);
        s = valid ? s : -1e30f;
        sv[jn][j] = s;
        pmax[j] = fmaxf(pmax[j], s);
      }
    }
    #pragma unroll
    for (int off = 1; off < 16; off <<= 1)
      #pragma unroll
      for (int j = 0; j < 4; ++j) pmax[j] = fmaxf(pmax[j], __shfl_xor(pmax[j], off, 64));
    // ---- online softmax update ----
    float rescale[4], rsum[4];
    #pragma unroll
    for (int j = 0; j < 4; ++j) {
      float mn = fmaxf(m_run[j], pmax[j]);
      rescale[j] = __expf(m_run[j] - mn);
      m_run[j] = mn;
      rsum[j] = 0.f;
    }
    __syncthreads();   // prior P reads complete (loop is block-uniform)
    #pragma unroll
    for (int jn = 0; jn < 4; ++jn)
      #pragma unroll
      for (int j = 0; j < 4; ++j) {
        float p = __expf(sv[jn][j] - m_run[j]);
        rsum[j] += p;
        p_lds[w][(hi4 * 4 + j) * 64 + jn * 16 + lo16] = f2bf(p);
      }
    #pragma unroll
    for (int off = 1; off < 16; off <<= 1)
      #pragma unroll
      for (int j = 0; j < 4; ++j) rsum[j] += __shfl_xor(rsum[j], off, 64);
    #pragma unroll
    for (int j = 0; j < 4; ++j) l_run[j] = l_run[j] * rescale[j] + rsum[j];
    f32x4 rs4;
    #pragma unroll
    for (int j = 0; j < 4; ++j) rs4[j] = rescale[j];
    #pragma unroll
    for (int dn = 0; dn < 8; ++dn) acc_o[dn] *= rs4;
    __syncthreads();   // P visible
    // ---- PV ----
    #pragma unroll
    for (int kkp = 0; kkp < 2; ++kkp) {
      bf16x8 ap = *(const bf16x8*)&p_lds[w][lo16 * 64 + kkp * 32 + hi4 * 8];
      const u16* vbase = vt + ((size_t)g * HDIM + lo16) * S_LEN + jt * 64 + kkp * 32 + hi4 * 8;
      #pragma unroll
      for (int dn = 0; dn < 8; ++dn) {
        bf16x8 bv = *(const bf16x8*)(vbase + (size_t)dn * 16 * S_LEN);
        acc_o[dn] = __builtin_amdgcn_mfma_f32_16x16x32_bf16(ap, bv, acc_o[dn], 0, 0, 0);
      }
    }
  }
  // ---- finalize: divide by (l + exp(sb - m)) and store ----
  float inv[4];
  #pragma unroll
  for (int j = 0; j < 4; ++j) inv[j] = 1.f / (l_run[j] + __expf(sb - m_run[j]));
  #pragma unroll
  for (int dn = 0; dn < 8; ++dn)
    #pragma unroll
    for (int j = 0; j < 4; ++j) {
      int m = r0 + hi4 * 4 + j;
      int col = h * HDIM + dn * 16 + lo16;
      ob[(size_t)m * DM + col] = f2bf(acc_o[dn][j] * inv[j]);
    }
}

extern "C" void kernel_launch(void* const* d_in, const int* in_sizes, int n_in,
                              void* d_out, int out_size, void* d_ws, size_t ws_size,
                              hipStream_t stream) {
  const float* x  = (const float*)d_in[0];
  const float* sb = (const float*)d_in[1];
  const float* wq = (const float*)d_in[2];
  const float* bq = (const float*)d_in[3];
  const float* wk = (const float*)d_in[4];
  const float* bk = (const float*)d_in[5];
  const float* wv = (const float*)d_in[6];
  const float* bv = (const float*)d_in[7];
  const float* wo = (const float*)d_in[8];
  const float* bo = (const float*)d_in[9];
  float* out = (float*)d_out;
  char* ws = (char*)d_ws;

  u16* xb    = (u16*)(ws + OFF_XB);
  u16* wqkvb = (u16*)(ws + OFF_WQKV);
  u16* wob   = (u16*)(ws + OFF_WO);
  u16* qh    = (u16*)(ws + OFF_QH);
  u16* kh    = (u16*)(ws + OFF_KH);
  u16* vt    = (u16*)(ws + OFF_VT);
  u16* ob    = (u16*)(ws + OFF_OB);

  prep_kernel<<<dim3(6656), dim3(256), 0, stream>>>(x, wq, wk, wv, wo, xb, wqkvb, wob);
  gemm_bt<0><<<dim3(32, 12), dim3(256), 0, stream>>>(xb, wqkvb, bq, bk, bv, qh, kh, vt, nullptr);
  attn_kernel<<<dim3(64, 8), dim3(256), 0, stream>>>(qh, kh, vt, sb, ob);
  gemm_bt<1><<<dim3(32, 8), dim3(256), 0, stream>>>(ob, wob, bo, nullptr, nullptr,
                                                    nullptr, nullptr, nullptr, out);
}

// Round 2
// 113.626 us; speedup vs baseline: 1.0097x; 1.0097x over previous
//
#include <hip/hip_runtime.h>

#define S_LEN 4096
#define DM    1024
#define NH    8
#define NKV   2
#define HDIM  128
#define WINSZ 256

typedef unsigned short u16;
typedef float f32x4 __attribute__((ext_vector_type(4)));
typedef short bf16x8 __attribute__((ext_vector_type(8)));

// ---------- workspace layout (bytes) ----------
static const size_t OFF_XB   = 0;          // x bf16 [4096][1024]            8388608
static const size_t OFF_WQKV = 8388608;    // Wq|Wk|Wv bf16 [1536][1024]     3145728
static const size_t OFF_WO   = 11534336;   // Wo bf16 [1024][1024]           2097152
static const size_t OFF_QH   = 13631488;   // q bf16 [8][4096][128]          8388608
static const size_t OFF_KH   = 22020096;   // k bf16 [2][4096][128]          2097152
static const size_t OFF_VT   = 24117248;   // v^T bf16 [2][128][4096]        2097152
static const size_t OFF_OB   = 26214400;   // attn out bf16 [4096][1024]     8388608

__device__ __forceinline__ u16 f2bf(float f) {
  union { float f; unsigned int u; } v; v.f = f;
  unsigned int u = v.u;
  u += 0x7fffu + ((u >> 16) & 1u);   // RNE
  return (u16)(u >> 16);
}

__device__ __forceinline__ void gload_lds16(const u16* g, u16* l) {
  __builtin_amdgcn_global_load_lds((const __attribute__((address_space(1))) void*)g,
                                   (__attribute__((address_space(3))) void*)l, 16, 0, 0);
}

// ---------------- prep: f32 -> bf16 conversions ----------------
__global__ __launch_bounds__(256) void prep_kernel(
    const float* __restrict__ x,  const float* __restrict__ wq,
    const float* __restrict__ wk, const float* __restrict__ wv,
    const float* __restrict__ wo,
    u16* __restrict__ xb, u16* __restrict__ wqkvb, u16* __restrict__ wob) {
  int i = blockIdx.x * 256 + threadIdx.x;       // one float4 per thread
  const float* src; u16* dst;
  if (i < 1048576)      { src = x  + (size_t)i * 4;               dst = xb + (size_t)i * 4; }
  else if (i < 1310720) { int j = i - 1048576; src = wq + (size_t)j*4; dst = wqkvb + (size_t)j*4; }
  else if (i < 1376256) { int j = i - 1310720; src = wk + (size_t)j*4; dst = wqkvb + 1048576 + (size_t)j*4; }
  else if (i < 1441792) { int j = i - 1376256; src = wv + (size_t)j*4; dst = wqkvb + 1310720 + (size_t)j*4; }
  else                  { int j = i - 1441792; src = wo + (size_t)j*4; dst = wob + (size_t)j*4; }
  float4 v = *(const float4*)src;
  ushort4 o;
  o.x = f2bf(v.x); o.y = f2bf(v.y); o.z = f2bf(v.z); o.w = f2bf(v.w);
  *(ushort4*)dst = o;
}

// ---------------- GEMM: C[m][n] = sum_k A[m][k]*B[n][k]  (both K-major) ----------------
// 64x128 tile, BK=64, 4 waves (each 32x64 = 2x4 16x16x32 frags), global_load_lds staging.
// grid (64, N/128); XCD-swizzled block ids. EPI 0: scatter qh/kh/vt (+bias). EPI 1: f32 out.
template<int EPI>
__global__ __launch_bounds__(256) void gemm_bt(
    const u16* __restrict__ A, const u16* __restrict__ B,
    const float* __restrict__ b0, const float* __restrict__ b1, const float* __restrict__ b2,
    u16* __restrict__ qh, u16* __restrict__ kh, u16* __restrict__ vt,
    float* __restrict__ outf) {
  __shared__ __align__(16) u16 As[64 * 64];     // 8 KB
  __shared__ __align__(16) u16 Bs[128 * 64];    // 16 KB
  const int tid = threadIdx.x;
  const int w = tid >> 6, l = tid & 63;
  const int lo16 = l & 15, hi4 = l >> 4;

  // bijective XCD-aware swizzle (nwg % 8 == 0 for both launches; gridDim.x == 64)
  const int nwg = gridDim.x * gridDim.y;
  const int lin = blockIdx.y * gridDim.x + blockIdx.x;
  const int s = (lin & 7) * (nwg >> 3) + (lin >> 3);
  const int m0 = (s & 63) * 64;
  const int n0 = (s >> 6) * 128;

  const int wm = w >> 1, wn = w & 1;
  const int K = 1024;

  f32x4 acc[2][4] = {};

  const int lr = l >> 3;         // row within 8-row chunk
  const int lc = (l & 7) * 8;    // elem col within 64-wide row

  for (int kt = 0; kt < K; kt += 64) {
    #pragma unroll
    for (int it = 0; it < 6; ++it) {
      int c = w * 6 + it;                       // 24 chunks: 8 for As, 16 for Bs
      if (c < 8) {
        int row = c * 8 + lr;
        gload_lds16(A + (size_t)(m0 + row) * K + kt + lc, (u16*)((char*)As + c * 1024));
      } else {
        int cc = c - 8;
        int row = cc * 8 + lr;
        gload_lds16(B + (size_t)(n0 + row) * K + kt + lc, (u16*)((char*)Bs + cc * 1024));
      }
    }
    __syncthreads();
    #pragma unroll
    for (int kk = 0; kk < 2; ++kk) {
      bf16x8 af[2], bfr[4];
      const int colb = (kk * 32 + hi4 * 8) * 2;   // byte offset in 128B row
      #pragma unroll
      for (int f = 0; f < 2; ++f)
        af[f] = *(const bf16x8*)((const char*)As + (wm * 32 + f * 16 + lo16) * 128 + colb);
      #pragma unroll
      for (int fn = 0; fn < 4; ++fn)
        bfr[fn] = *(const bf16x8*)((const char*)Bs + (wn * 64 + fn * 16 + lo16) * 128 + colb);
      #pragma unroll
      for (int fm = 0; fm < 2; ++fm)
        #pragma unroll
        for (int fn = 0; fn < 4; ++fn)
          acc[fm][fn] = __builtin_amdgcn_mfma_f32_16x16x32_bf16(af[fm], bfr[fn], acc[fm][fn], 0, 0, 0);
    }
    __syncthreads();
  }

  // epilogue: row = m0+wm*32+fm*16+hi4*4+j ; col = n0+wn*64+fn*16+lo16
  #pragma unroll
  for (int fm = 0; fm < 2; ++fm) {
    #pragma unroll
    for (int fn = 0; fn < 4; ++fn) {
      f32x4 c = acc[fm][fn];
      const int col  = n0 + wn * 64 + fn * 16 + lo16;
      const int rowb = m0 + wm * 32 + fm * 16 + hi4 * 4;
      if (EPI == 0) {
        float bias = (col < 1024) ? b0[col] : (col < 1280 ? b1[col - 1024] : b2[col - 1280]);
        #pragma unroll
        for (int j = 0; j < 4; ++j) {
          int m = rowb + j;
          u16 hb = f2bf(c[j] + bias);
          if (col < 1024) {
            qh[((size_t)(col >> 7) * S_LEN + m) * HDIM + (col & 127)] = hb;
          } else if (col < 1280) {
            int cc = col - 1024;
            kh[((size_t)(cc >> 7) * S_LEN + m) * HDIM + (cc & 127)] = hb;
          } else {
            int cc = col - 1280;
            vt[((size_t)(cc >> 7) * HDIM + (cc & 127)) * S_LEN + m] = hb;
          }
        }
      } else {
        float bias = b0[col];
        #pragma unroll
        for (int j = 0; j < 4; ++j)
          outf[(size_t)(rowb + j) * DM + col] = c[j] + bias;
      }
    }
  }
}

// ---------------- attention: 1 wave / 16 q-rows, non-online softmax ----------------
// grid (S/16, H), 64 threads. All <=5 key tiles' scores held in regs; single
// max/exp pass; P staged in XOR-swizzled LDS; no barriers (single wave).
__global__ __launch_bounds__(64) void attn_kernel(
    const u16* __restrict__ qh, const u16* __restrict__ kh,
    const u16* __restrict__ vt, const float* __restrict__ sb_ptr,
    u16* __restrict__ ob) {
  const int r0 = blockIdx.x * 16;
  const int h  = blockIdx.y;
  const int g  = h >> 2;                 // H/KV = 4
  const int l  = threadIdx.x;
  const int lo16 = l & 15, hi4 = l >> 4;
  const float sb = *sb_ptr;
  const float scale = 0.08838834764831845f;   // 1/sqrt(128)

  __shared__ __align__(16) u16 p_lds[5 * 1024];   // 5 tiles x [16 rows][64 keys], 10 KB

  // Q fragments
  bf16x8 aq[4];
  {
    const u16* qbase = qh + ((size_t)h * S_LEN + r0 + lo16) * HDIM + hi4 * 8;
    #pragma unroll
    for (int kk = 0; kk < 4; ++kk) aq[kk] = *(const bf16x8*)(qbase + kk * 32);
  }

  int lo = r0 - (WINSZ - 1); if (lo < 0) lo = 0;
  const int jt0 = lo >> 6;
  const int jtN = (r0 + 15) >> 6;
  const int nt  = jtN - jt0 + 1;         // 1..5

  f32x4 sc[5][4];
  #pragma unroll
  for (int t = 0; t < 5; ++t)
    #pragma unroll
    for (int jn = 0; jn < 4; ++jn)
      sc[t][jn] = (f32x4){0.f, 0.f, 0.f, 0.f};

  // ---- QK^T, all tiles (independent MFMA streams -> ILP) ----
  #pragma unroll
  for (int t = 0; t < 5; ++t) {
    if (t < nt) {
      const u16* kb = kh + ((size_t)g * S_LEN + (jt0 + t) * 64 + lo16) * HDIM + hi4 * 8;
      #pragma unroll
      for (int jn = 0; jn < 4; ++jn) {
        #pragma unroll
        for (int kk = 0; kk < 4; ++kk) {
          bf16x8 bk = *(const bf16x8*)(kb + jn * 16 * HDIM + kk * 32);
          sc[t][jn] = __builtin_amdgcn_mfma_f32_16x16x32_bf16(aq[kk], bk, sc[t][jn], 0, 0, 0);
        }
      }
    }
  }

  // ---- mask (edge tiles only) + scale + full-row max ----
  float pmax[4] = {-3e38f, -3e38f, -3e38f, -3e38f};
  #pragma unroll
  for (int t = 0; t < 5; ++t) {
    if (t < nt) {
      const int jt = jt0 + t;
      const bool edge = (jt == jtN) || (jt * 64 < r0 - 240);   // causal / window-lower edge
      #pragma unroll
      for (int jn = 0; jn < 4; ++jn) {
        const int jg = jt * 64 + jn * 16 + lo16;
        #pragma unroll
        for (int j = 0; j < 4; ++j) {
          float s2 = sc[t][jn][j] * scale;
          if (edge) {
            const int ig = r0 + hi4 * 4 + j;
            bool valid = (jg <= ig) && (jg > ig - WINSZ);
            s2 = valid ? s2 : -1e30f;
          }
          sc[t][jn][j] = s2;
          pmax[j] = fmaxf(pmax[j], s2);
        }
      }
    }
  }
  #pragma unroll
  for (int off = 1; off < 16; off <<= 1)
    #pragma unroll
    for (int j = 0; j < 4; ++j) pmax[j] = fmaxf(pmax[j], __shfl_xor(pmax[j], off, 64));
  float m[4], rsum[4];
  #pragma unroll
  for (int j = 0; j < 4; ++j) { m[j] = fmaxf(pmax[j], sb); rsum[j] = 0.f; }

  // ---- exp + P -> LDS (swizzled: byte ^= (row&7)<<4) + row sums ----
  const int wbase = hi4 * 512 + lo16 * 2;        // (hi4*4)*128 + lo16*2
  #pragma unroll
  for (int t = 0; t < 5; ++t) {
    if (t < nt) {
      #pragma unroll
      for (int jn = 0; jn < 4; ++jn) {
        #pragma unroll
        for (int j = 0; j < 4; ++j) {
          float p = __expf(sc[t][jn][j] - m[j]);
          rsum[j] += p;
          int addr = t * 2048 + wbase + j * 128 + jn * 32;   // row = hi4*4+j, col = jn*16+lo16
          addr ^= ((((hi4 & 1) << 2) + j) << 4);             // (row&7)<<4
          *(u16*)((char*)p_lds + addr) = f2bf(p);
        }
      }
    }
  }
  #pragma unroll
  for (int off = 1; off < 16; off <<= 1)
    #pragma unroll
    for (int j = 0; j < 4; ++j) rsum[j] += __shfl_xor(rsum[j], off, 64);

  // ---- PV ----
  f32x4 acc_o[8] = {};
  const int rbase = lo16 * 128 + hi4 * 16;
  const int rswz  = (lo16 & 7) << 4;
  #pragma unroll
  for (int t = 0; t < 5; ++t) {
    if (t < nt) {
      const u16* vb = vt + ((size_t)g * HDIM + lo16) * S_LEN + (jt0 + t) * 64 + hi4 * 8;
      #pragma unroll
      for (int kkp = 0; kkp < 2; ++kkp) {
        bf16x8 ap = *(const bf16x8*)((const char*)p_lds + ((t * 2048 + rbase + kkp * 64) ^ rswz));
        #pragma unroll
        for (int dn = 0; dn < 8; ++dn) {
          bf16x8 bv = *(const bf16x8*)(vb + kkp * 32 + (size_t)dn * 16 * S_LEN);
          acc_o[dn] = __builtin_amdgcn_mfma_f32_16x16x32_bf16(ap, bv, acc_o[dn], 0, 0, 0);
        }
      }
    }
  }

  // ---- finalize: divide by (sum + exp(sb - m)) and store ----
  float inv[4];
  #pragma unroll
  for (int j = 0; j < 4; ++j) inv[j] = 1.f / (rsum[j] + __expf(sb - m[j]));
  #pragma unroll
  for (int dn = 0; dn < 8; ++dn)
    #pragma unroll
    for (int j = 0; j < 4; ++j)
      ob[(size_t)(r0 + hi4 * 4 + j) * DM + h * HDIM + dn * 16 + lo16] = f2bf(acc_o[dn][j] * inv[j]);
}

extern "C" void kernel_launch(void* const* d_in, const int* in_sizes, int n_in,
                              void* d_out, int out_size, void* d_ws, size_t ws_size,
                              hipStream_t stream) {
  const float* x  = (const float*)d_in[0];
  const float* sb = (const float*)d_in[1];
  const float* wq = (const float*)d_in[2];
  const float* bq = (const float*)d_in[3];
  const float* wk = (const float*)d_in[4];
  const float* bk = (const float*)d_in[5];
  const float* wv = (const float*)d_in[6];
  const float* bv = (const float*)d_in[7];
  const float* wo = (const float*)d_in[8];
  const float* bo = (const float*)d_in[9];
  float* out = (float*)d_out;
  char* ws = (char*)d_ws;

  u16* xb    = (u16*)(ws + OFF_XB);
  u16* wqkvb = (u16*)(ws + OFF_WQKV);
  u16* wob   = (u16*)(ws + OFF_WO);
  u16* qh    = (u16*)(ws + OFF_QH);
  u16* kh    = (u16*)(ws + OFF_KH);
  u16* vt    = (u16*)(ws + OFF_VT);
  u16* ob    = (u16*)(ws + OFF_OB);

  prep_kernel<<<dim3(6656), dim3(256), 0, stream>>>(x, wq, wk, wv, wo, xb, wqkvb, wob);
  gemm_bt<0><<<dim3(64, 12), dim3(256), 0, stream>>>(xb, wqkvb, bq, bk, bv, qh, kh, vt, nullptr);
  attn_kernel<<<dim3(256, 8), dim3(64), 0, stream>>>(qh, kh, vt, sb, ob);
  gemm_bt<1><<<dim3(64, 8), dim3(256), 0, stream>>>(ob, wob, bo, nullptr, nullptr,
                                                    nullptr, nullptr, nullptr, out);
}

// Round 3
// 86.307 us; speedup vs baseline: 1.3293x; 1.3165x over previous
//
#include <hip/hip_runtime.h>

#define S_LEN 4096
#define DM    1024
#define NH    8
#define NKV   2
#define HDIM  128
#define WINSZ 256

typedef unsigned short u16;
typedef float f32x4 __attribute__((ext_vector_type(4)));
typedef short bf16x8 __attribute__((ext_vector_type(8)));

// ---------- workspace layout (bytes) ----------
static const size_t OFF_XB   = 0;          // x bf16 [4096][1024]            8388608
static const size_t OFF_WQKV = 8388608;    // Wq|Wk|Wv bf16 [1536][1024]     3145728
static const size_t OFF_WO   = 11534336;   // Wo bf16 [1024][1024]           2097152
static const size_t OFF_QH   = 13631488;   // q bf16 [8][4096][128]          8388608
static const size_t OFF_KH   = 22020096;   // k bf16 [2][4096][128]          2097152
static const size_t OFF_VT   = 24117248;   // v^T bf16 [2][128][4096]        2097152
static const size_t OFF_OB   = 26214400;   // attn out bf16 [4096][1024]     8388608

__device__ __forceinline__ u16 f2bf(float f) {
  union { float f; unsigned int u; } v; v.f = f;
  unsigned int u = v.u;
  u += 0x7fffu + ((u >> 16) & 1u);   // RNE
  return (u16)(u >> 16);
}

__device__ __forceinline__ void gload_lds16(const u16* g, u16* l) {
  __builtin_amdgcn_global_load_lds((const __attribute__((address_space(1))) void*)g,
                                   (__attribute__((address_space(3))) void*)l, 16, 0, 0);
}

// ---------------- prep: f32 -> bf16 conversions ----------------
__global__ __launch_bounds__(256) void prep_kernel(
    const float* __restrict__ x,  const float* __restrict__ wq,
    const float* __restrict__ wk, const float* __restrict__ wv,
    const float* __restrict__ wo,
    u16* __restrict__ xb, u16* __restrict__ wqkvb, u16* __restrict__ wob) {
  int i = blockIdx.x * 256 + threadIdx.x;       // one float4 per thread
  const float* src; u16* dst;
  if (i < 1048576)      { src = x  + (size_t)i * 4;               dst = xb + (size_t)i * 4; }
  else if (i < 1310720) { int j = i - 1048576; src = wq + (size_t)j*4; dst = wqkvb + (size_t)j*4; }
  else if (i < 1376256) { int j = i - 1310720; src = wk + (size_t)j*4; dst = wqkvb + 1048576 + (size_t)j*4; }
  else if (i < 1441792) { int j = i - 1376256; src = wv + (size_t)j*4; dst = wqkvb + 1310720 + (size_t)j*4; }
  else                  { int j = i - 1441792; src = wo + (size_t)j*4; dst = wob + (size_t)j*4; }
  float4 v = *(const float4*)src;
  ushort4 o;
  o.x = f2bf(v.x); o.y = f2bf(v.y); o.z = f2bf(v.z); o.w = f2bf(v.w);
  *(ushort4*)dst = o;
}

// ---------------- GEMM: C[m][n] = sum_k A[m][k]*B[n][k]  (both K-major) ----------------
// 64x128 tile, BK=64, 4 waves (each 32x64 = 2x4 16x16x32 frags), global_load_lds staging.
template<int EPI>
__global__ __launch_bounds__(256) void gemm_bt(
    const u16* __restrict__ A, const u16* __restrict__ B,
    const float* __restrict__ b0, const float* __restrict__ b1, const float* __restrict__ b2,
    u16* __restrict__ qh, u16* __restrict__ kh, u16* __restrict__ vt,
    float* __restrict__ outf) {
  __shared__ __align__(16) u16 As[64 * 64];     // 8 KB
  __shared__ __align__(16) u16 Bs[128 * 64];    // 16 KB
  const int tid = threadIdx.x;
  const int w = tid >> 6, l = tid & 63;
  const int lo16 = l & 15, hi4 = l >> 4;

  const int nwg = gridDim.x * gridDim.y;
  const int lin = blockIdx.y * gridDim.x + blockIdx.x;
  const int s = (lin & 7) * (nwg >> 3) + (lin >> 3);
  const int m0 = (s & 63) * 64;
  const int n0 = (s >> 6) * 128;

  const int wm = w >> 1, wn = w & 1;
  const int K = 1024;

  f32x4 acc[2][4] = {};

  const int lr = l >> 3;         // row within 8-row chunk
  const int lc = (l & 7) * 8;    // elem col within 64-wide row

  for (int kt = 0; kt < K; kt += 64) {
    #pragma unroll
    for (int it = 0; it < 6; ++it) {
      int c = w * 6 + it;                       // 24 chunks: 8 for As, 16 for Bs
      if (c < 8) {
        int row = c * 8 + lr;
        gload_lds16(A + (size_t)(m0 + row) * K + kt + lc, (u16*)((char*)As + c * 1024));
      } else {
        int cc = c - 8;
        int row = cc * 8 + lr;
        gload_lds16(B + (size_t)(n0 + row) * K + kt + lc, (u16*)((char*)Bs + cc * 1024));
      }
    }
    __syncthreads();
    #pragma unroll
    for (int kk = 0; kk < 2; ++kk) {
      bf16x8 af[2], bfr[4];
      const int colb = (kk * 32 + hi4 * 8) * 2;   // byte offset in 128B row
      #pragma unroll
      for (int f = 0; f < 2; ++f)
        af[f] = *(const bf16x8*)((const char*)As + (wm * 32 + f * 16 + lo16) * 128 + colb);
      #pragma unroll
      for (int fn = 0; fn < 4; ++fn)
        bfr[fn] = *(const bf16x8*)((const char*)Bs + (wn * 64 + fn * 16 + lo16) * 128 + colb);
      #pragma unroll
      for (int fm = 0; fm < 2; ++fm)
        #pragma unroll
        for (int fn = 0; fn < 4; ++fn)
          acc[fm][fn] = __builtin_amdgcn_mfma_f32_16x16x32_bf16(af[fm], bfr[fn], acc[fm][fn], 0, 0, 0);
    }
    __syncthreads();
  }

  #pragma unroll
  for (int fm = 0; fm < 2; ++fm) {
    #pragma unroll
    for (int fn = 0; fn < 4; ++fn) {
      f32x4 c = acc[fm][fn];
      const int col  = n0 + wn * 64 + fn * 16 + lo16;
      const int rowb = m0 + wm * 32 + fm * 16 + hi4 * 4;
      if (EPI == 0) {
        float bias = (col < 1024) ? b0[col] : (col < 1280 ? b1[col - 1024] : b2[col - 1280]);
        #pragma unroll
        for (int j = 0; j < 4; ++j) {
          int m = rowb + j;
          u16 hb = f2bf(c[j] + bias);
          if (col < 1024) {
            qh[((size_t)(col >> 7) * S_LEN + m) * HDIM + (col & 127)] = hb;
          } else if (col < 1280) {
            int cc = col - 1024;
            kh[((size_t)(cc >> 7) * S_LEN + m) * HDIM + (cc & 127)] = hb;
          } else {
            int cc = col - 1280;
            vt[((size_t)(cc >> 7) * HDIM + (cc & 127)) * S_LEN + m] = hb;
          }
        }
      } else {
        float bias = b0[col];
        #pragma unroll
        for (int j = 0; j < 4; ++j)
          outf[(size_t)(rowb + j) * DM + col] = c[j] + bias;
      }
    }
  }
}

// ---------------- attention: 4 waves / 64 q-rows, LDS-staged K/V ----------------
// grid (S/64, H), 256 thr. Wave w: q rows r0+w*16..+15. Two-phase: stage K per
// tile -> QK^T (all <=5 tiles, scores in regs) -> one softmax -> stage V per
// tile -> PV. K/V LDS XOR-swizzled via pre-swizzled global_load_lds source.
__global__ __launch_bounds__(256) void attn_kernel(
    const u16* __restrict__ qh, const u16* __restrict__ kh,
    const u16* __restrict__ vt, const float* __restrict__ sb_ptr,
    u16* __restrict__ ob) {
  __shared__ __align__(16) u16 kv_lds[8192];    // 16KB: K tile [64][256B] / V tile [128][128B]
  __shared__ __align__(16) u16 p_lds[20480];    // 40KB: wave w, tile t at (w*5+t)*2048 bytes
  const int r0 = blockIdx.x * 64;
  const int h  = blockIdx.y;
  const int g  = h >> 2;                 // H/KV = 4
  const int tid = threadIdx.x;
  const int w = tid >> 6, l = tid & 63;
  const int lo16 = l & 15, hi4 = l >> 4;
  const int rw = r0 + w * 16;
  const float sb = *sb_ptr;
  const float scale = 0.08838834764831845f;   // 1/sqrt(128)

  // Q fragments
  bf16x8 aq[4];
  {
    const u16* qbase = qh + ((size_t)h * S_LEN + rw + lo16) * HDIM + hi4 * 8;
    #pragma unroll
    for (int kk = 0; kk < 4; ++kk) aq[kk] = *(const bf16x8*)(qbase + kk * 32);
  }

  int lo = r0 - (WINSZ - 1); if (lo < 0) lo = 0;
  const int jt0 = lo >> 6;
  const int nt  = (r0 >> 6) - jt0 + 1;   // 1..5 (block-uniform)

  f32x4 sc[5][4];
  #pragma unroll
  for (int t = 0; t < 5; ++t)
    #pragma unroll
    for (int jn = 0; jn < 4; ++jn) sc[t][jn] = (f32x4){0.f, 0.f, 0.f, 0.f};

  // ---- phase 1: stage K tile, QK^T ----
  #pragma unroll
  for (int t = 0; t < 5; ++t) {
    if (t < nt) {
      const int jt = jt0 + t;
      #pragma unroll
      for (int it = 0; it < 4; ++it) {
        int r  = (w * 4 + it) * 4 + (l >> 4);                 // K row 0..63
        int cb = ((l & 15) * 16) ^ ((r & 7) << 4);            // pre-swizzled col byte
        gload_lds16(kh + ((size_t)g * S_LEN + jt * 64 + r) * HDIM + (cb >> 1),
                    kv_lds + (w * 4 + it) * 512);
      }
    }
    __syncthreads();
    if (t < nt) {
      #pragma unroll
      for (int jn = 0; jn < 4; ++jn) {
        const int R = jn * 16 + lo16;
        #pragma unroll
        for (int kk = 0; kk < 4; ++kk) {
          int addr = R * 256 + ((kk * 64 + hi4 * 16) ^ ((R & 7) << 4));
          bf16x8 bk = *(const bf16x8*)((const char*)kv_lds + addr);
          sc[t][jn] = __builtin_amdgcn_mfma_f32_16x16x32_bf16(aq[kk], bk, sc[t][jn], 0, 0, 0);
        }
      }
    }
    __syncthreads();
  }

  // ---- softmax: mask + scale + max, exp, P->LDS, sums (no barriers: per-wave P) ----
  float pmax[4] = {-3e38f, -3e38f, -3e38f, -3e38f};
  #pragma unroll
  for (int t = 0; t < 5; ++t) {
    if (t < nt) {
      const int jt = jt0 + t;
      const bool edge = (jt * 64 + 63 > rw) || (jt * 64 < rw - 240);
      #pragma unroll
      for (int jn = 0; jn < 4; ++jn) {
        const int jg = jt * 64 + jn * 16 + lo16;
        #pragma unroll
        for (int j = 0; j < 4; ++j) {
          float s2 = sc[t][jn][j] * scale;
          if (edge) {
            const int ig = rw + hi4 * 4 + j;
            bool valid = (jg <= ig) && (jg > ig - WINSZ);
            s2 = valid ? s2 : -1e30f;
          }
          sc[t][jn][j] = s2;
          pmax[j] = fmaxf(pmax[j], s2);
        }
      }
    }
  }
  #pragma unroll
  for (int off = 1; off < 16; off <<= 1)
    #pragma unroll
    for (int j = 0; j < 4; ++j) pmax[j] = fmaxf(pmax[j], __shfl_xor(pmax[j], off, 64));
  float m[4], rsum[4];
  #pragma unroll
  for (int j = 0; j < 4; ++j) { m[j] = fmaxf(pmax[j], sb); rsum[j] = 0.f; }

  #pragma unroll
  for (int t = 0; t < 5; ++t) {
    if (t < nt) {
      #pragma unroll
      for (int jn = 0; jn < 4; ++jn) {
        #pragma unroll
        for (int j = 0; j < 4; ++j) {
          float p = __expf(sc[t][jn][j] - m[j]);
          rsum[j] += p;
          int row = hi4 * 4 + j;
          int addr = (w * 5 + t) * 2048 + row * 128
                   + (((jn * 16 + lo16) * 2) ^ ((row & 7) << 4));
          *(u16*)((char*)p_lds + addr) = f2bf(p);
        }
      }
    }
  }
  #pragma unroll
  for (int off = 1; off < 16; off <<= 1)
    #pragma unroll
    for (int j = 0; j < 4; ++j) rsum[j] += __shfl_xor(rsum[j], off, 64);

  // ---- phase 2: stage V tile, PV ----
  f32x4 acc_o[8] = {};
  #pragma unroll
  for (int t = 0; t < 5; ++t) {
    if (t < nt) {
      const int jt = jt0 + t;
      #pragma unroll
      for (int it = 0; it < 4; ++it) {
        int r  = (w * 4 + it) * 8 + (l >> 3);                 // V row (d) 0..127
        int cb = 16 * ((l & 7) ^ (l >> 3));                   // pre-swizzled col byte
        gload_lds16(vt + ((size_t)g * HDIM + r) * S_LEN + jt * 64 + (cb >> 1),
                    kv_lds + (w * 4 + it) * 512);
      }
    }
    __syncthreads();
    if (t < nt) {
      #pragma unroll
      for (int kkp = 0; kkp < 2; ++kkp) {
        int pa = (w * 5 + t) * 2048 + lo16 * 128
               + ((kkp * 64 + hi4 * 16) ^ ((lo16 & 7) << 4));
        bf16x8 ap = *(const bf16x8*)((const char*)p_lds + pa);
        #pragma unroll
        for (int dn = 0; dn < 8; ++dn) {
          const int R = dn * 16 + lo16;
          int va = R * 128 + ((kkp * 64 + hi4 * 16) ^ ((R & 7) << 4));
          bf16x8 bv = *(const bf16x8*)((const char*)kv_lds + va);
          acc_o[dn] = __builtin_amdgcn_mfma_f32_16x16x32_bf16(ap, bv, acc_o[dn], 0, 0, 0);
        }
      }
    }
    __syncthreads();
  }

  // ---- finalize ----
  float inv[4];
  #pragma unroll
  for (int j = 0; j < 4; ++j) inv[j] = 1.f / (rsum[j] + __expf(sb - m[j]));
  #pragma unroll
  for (int dn = 0; dn < 8; ++dn)
    #pragma unroll
    for (int j = 0; j < 4; ++j)
      ob[(size_t)(rw + hi4 * 4 + j) * DM + h * HDIM + dn * 16 + lo16] = f2bf(acc_o[dn][j] * inv[j]);
}

extern "C" void kernel_launch(void* const* d_in, const int* in_sizes, int n_in,
                              void* d_out, int out_size, void* d_ws, size_t ws_size,
                              hipStream_t stream) {
  const float* x  = (const float*)d_in[0];
  const float* sb = (const float*)d_in[1];
  const float* wq = (const float*)d_in[2];
  const float* bq = (const float*)d_in[3];
  const float* wk = (const float*)d_in[4];
  const float* bk = (const float*)d_in[5];
  const float* wv = (const float*)d_in[6];
  const float* bv = (const float*)d_in[7];
  const float* wo = (const float*)d_in[8];
  const float* bo = (const float*)d_in[9];
  float* out = (float*)d_out;
  char* ws = (char*)d_ws;

  u16* xb    = (u16*)(ws + OFF_XB);
  u16* wqkvb = (u16*)(ws + OFF_WQKV);
  u16* wob   = (u16*)(ws + OFF_WO);
  u16* qh    = (u16*)(ws + OFF_QH);
  u16* kh    = (u16*)(ws + OFF_KH);
  u16* vt    = (u16*)(ws + OFF_VT);
  u16* ob    = (u16*)(ws + OFF_OB);

  prep_kernel<<<dim3(6656), dim3(256), 0, stream>>>(x, wq, wk, wv, wo, xb, wqkvb, wob);
  gemm_bt<0><<<dim3(64, 12), dim3(256), 0, stream>>>(xb, wqkvb, bq, bk, bv, qh, kh, vt, nullptr);
  attn_kernel<<<dim3(64, 8), dim3(256), 0, stream>>>(qh, kh, vt, sb, ob);
  gemm_bt<1><<<dim3(64, 8), dim3(256), 0, stream>>>(ob, wob, bo, nullptr, nullptr,
                                                    nullptr, nullptr, nullptr, out);
}

// Round 4
// 81.954 us; speedup vs baseline: 1.3999x; 1.0531x over previous
//
#include <hip/hip_runtime.h>

#define S_LEN 4096
#define DM    1024
#define NH    8
#define NKV   2
#define HDIM  128
#define WINSZ 256

typedef unsigned short u16;
typedef float f32x4 __attribute__((ext_vector_type(4)));
typedef short bf16x8 __attribute__((ext_vector_type(8)));

// ---------- workspace layout (bytes) ----------
static const size_t OFF_XB   = 0;          // x bf16 [4096][1024]            8388608
static const size_t OFF_WQKV = 8388608;    // Wq|Wk|Wv bf16 [1536][1024]     3145728
static const size_t OFF_WO   = 11534336;   // Wo bf16 [1024][1024]           2097152
static const size_t OFF_QH   = 13631488;   // q bf16 [8][4096][128]          8388608
static const size_t OFF_KH   = 22020096;   // k bf16 [2][4096][128]          2097152
static const size_t OFF_VT   = 24117248;   // v^T bf16 [2][128][4096]        2097152
static const size_t OFF_OB   = 26214400;   // attn out bf16 [4096][1024]     8388608

__device__ __forceinline__ u16 f2bf(float f) {
  union { float f; unsigned int u; } v; v.f = f;
  unsigned int u = v.u;
  u += 0x7fffu + ((u >> 16) & 1u);   // RNE
  return (u16)(u >> 16);
}

__device__ __forceinline__ void gload_lds16(const u16* g, u16* l) {
  __builtin_amdgcn_global_load_lds((const __attribute__((address_space(1))) void*)g,
                                   (__attribute__((address_space(3))) void*)l, 16, 0, 0);
}

// ---------------- prep: f32 -> bf16 conversions ----------------
__global__ __launch_bounds__(256) void prep_kernel(
    const float* __restrict__ x,  const float* __restrict__ wq,
    const float* __restrict__ wk, const float* __restrict__ wv,
    const float* __restrict__ wo,
    u16* __restrict__ xb, u16* __restrict__ wqkvb, u16* __restrict__ wob) {
  int i = blockIdx.x * 256 + threadIdx.x;       // one float4 per thread
  const float* src; u16* dst;
  if (i < 1048576)      { src = x  + (size_t)i * 4;               dst = xb + (size_t)i * 4; }
  else if (i < 1310720) { int j = i - 1048576; src = wq + (size_t)j*4; dst = wqkvb + (size_t)j*4; }
  else if (i < 1376256) { int j = i - 1310720; src = wk + (size_t)j*4; dst = wqkvb + 1048576 + (size_t)j*4; }
  else if (i < 1441792) { int j = i - 1376256; src = wv + (size_t)j*4; dst = wqkvb + 1310720 + (size_t)j*4; }
  else                  { int j = i - 1441792; src = wo + (size_t)j*4; dst = wob + (size_t)j*4; }
  float4 v = *(const float4*)src;
  ushort4 o;
  o.x = f2bf(v.x); o.y = f2bf(v.y); o.z = f2bf(v.z); o.w = f2bf(v.w);
  *(ushort4*)dst = o;
}

// ---------------- GEMM: C[m][n] = sum_k A[m][k]*B[n][k]  (both K-major) ----------------
// 64x128 tile, BK=64, 4 waves (each 32x64 = 2x4 16x16x32 frags).
// Double-buffered LDS: STAGE(t+1) issued BEFORE compute(t); one barrier/tile.
template<int EPI>
__global__ __launch_bounds__(256) void gemm_bt(
    const u16* __restrict__ A, const u16* __restrict__ B,
    const float* __restrict__ b0, const float* __restrict__ b1, const float* __restrict__ b2,
    u16* __restrict__ qh, u16* __restrict__ kh, u16* __restrict__ vt,
    float* __restrict__ outf) {
  __shared__ __align__(16) u16 As[2][64 * 64];     // 2 x 8 KB
  __shared__ __align__(16) u16 Bs[2][128 * 64];    // 2 x 16 KB
  const int tid = threadIdx.x;
  const int w = tid >> 6, l = tid & 63;
  const int lo16 = l & 15, hi4 = l >> 4;

  const int nwg = gridDim.x * gridDim.y;
  const int lin = blockIdx.y * gridDim.x + blockIdx.x;
  const int s = (lin & 7) * (nwg >> 3) + (lin >> 3);
  const int m0 = (s & 63) * 64;
  const int n0 = (s >> 6) * 128;

  const int wm = w >> 1, wn = w & 1;
  const int K = 1024;

  f32x4 acc[2][4] = {};

  const int lr = l >> 3;         // row within 8-row chunk
  const int lc = (l & 7) * 8;    // elem col within 64-wide row

  auto stage = [&](int buf, int kt) {
    #pragma unroll
    for (int it = 0; it < 6; ++it) {
      int c = w * 6 + it;                       // 24 chunks: 8 for As, 16 for Bs
      if (c < 8) {
        int row = c * 8 + lr;
        gload_lds16(A + (size_t)(m0 + row) * K + kt + lc, &As[buf][c * 512]);
      } else {
        int cc = c - 8;
        int row = cc * 8 + lr;
        gload_lds16(B + (size_t)(n0 + row) * K + kt + lc, &Bs[buf][cc * 512]);
      }
    }
  };

  stage(0, 0);
  __syncthreads();
  int buf = 0;
  for (int kt = 0; kt < K; kt += 64) {
    if (kt + 64 < K) stage(buf ^ 1, kt + 64);
    #pragma unroll
    for (int kk = 0; kk < 2; ++kk) {
      bf16x8 af[2], bfr[4];
      const int colb = (kk * 32 + hi4 * 8) * 2;   // byte offset in 128B row
      #pragma unroll
      for (int f = 0; f < 2; ++f)
        af[f] = *(const bf16x8*)((const char*)&As[buf][0] + (wm * 32 + f * 16 + lo16) * 128 + colb);
      #pragma unroll
      for (int fn = 0; fn < 4; ++fn)
        bfr[fn] = *(const bf16x8*)((const char*)&Bs[buf][0] + (wn * 64 + fn * 16 + lo16) * 128 + colb);
      #pragma unroll
      for (int fm = 0; fm < 2; ++fm)
        #pragma unroll
        for (int fn = 0; fn < 4; ++fn)
          acc[fm][fn] = __builtin_amdgcn_mfma_f32_16x16x32_bf16(af[fm], bfr[fn], acc[fm][fn], 0, 0, 0);
    }
    __syncthreads();   // drains prefetch vmcnt + protects buf reuse
    buf ^= 1;
  }

  #pragma unroll
  for (int fm = 0; fm < 2; ++fm) {
    #pragma unroll
    for (int fn = 0; fn < 4; ++fn) {
      f32x4 c = acc[fm][fn];
      const int col  = n0 + wn * 64 + fn * 16 + lo16;
      const int rowb = m0 + wm * 32 + fm * 16 + hi4 * 4;
      if (EPI == 0) {
        float bias = (col < 1024) ? b0[col] : (col < 1280 ? b1[col - 1024] : b2[col - 1280]);
        #pragma unroll
        for (int j = 0; j < 4; ++j) {
          int m = rowb + j;
          u16 hb = f2bf(c[j] + bias);
          if (col < 1024) {
            qh[((size_t)(col >> 7) * S_LEN + m) * HDIM + (col & 127)] = hb;
          } else if (col < 1280) {
            int cc = col - 1024;
            kh[((size_t)(cc >> 7) * S_LEN + m) * HDIM + (cc & 127)] = hb;
          } else {
            int cc = col - 1280;
            vt[((size_t)(cc >> 7) * HDIM + (cc & 127)) * S_LEN + m] = hb;
          }
        }
      } else {
        float bias = b0[col];
        #pragma unroll
        for (int j = 0; j < 4; ++j)
          outf[(size_t)(rowb + j) * DM + col] = c[j] + bias;
      }
    }
  }
}

// ---------------- attention: 4 waves / 64 q-rows, dbuf LDS-staged K/V ----------------
// grid (S/64, H), 256 thr. Prefetch K[t+1] under QK^T[t]; V[0] staged under the
// softmax; V[t+1] under PV[t]. One barrier per tile per phase.
__global__ __launch_bounds__(256) void attn_kernel(
    const u16* __restrict__ qh, const u16* __restrict__ kh,
    const u16* __restrict__ vt, const float* __restrict__ sb_ptr,
    u16* __restrict__ ob) {
  __shared__ __align__(16) u16 kv_lds[2][8192];  // 2 x 16KB: K tile [64][256B] / V tile [128][128B]
  __shared__ __align__(16) u16 p_lds[20480];     // 40KB: wave w, tile t at (w*5+t)*2048 bytes
  const int r0 = blockIdx.x * 64;
  const int h  = blockIdx.y;
  const int g  = h >> 2;                 // H/KV = 4
  const int tid = threadIdx.x;
  const int w = tid >> 6, l = tid & 63;
  const int lo16 = l & 15, hi4 = l >> 4;
  const int rw = r0 + w * 16;
  const float sb = *sb_ptr;
  const float scale = 0.08838834764831845f;   // 1/sqrt(128)

  // Q fragments
  bf16x8 aq[4];
  {
    const u16* qbase = qh + ((size_t)h * S_LEN + rw + lo16) * HDIM + hi4 * 8;
    #pragma unroll
    for (int kk = 0; kk < 4; ++kk) aq[kk] = *(const bf16x8*)(qbase + kk * 32);
  }

  int lo = r0 - (WINSZ - 1); if (lo < 0) lo = 0;
  const int jt0 = lo >> 6;
  const int nt  = (r0 >> 6) - jt0 + 1;   // 1..5 (block-uniform)

  auto stageK = [&](int buf, int jt) {
    #pragma unroll
    for (int it = 0; it < 4; ++it) {
      int ch = w * 4 + it;
      int r  = ch * 4 + (l >> 4);                            // K row 0..63
      int cb = ((l & 15) * 16) ^ ((r & 7) << 4);             // pre-swizzled col byte
      gload_lds16(kh + ((size_t)g * S_LEN + jt * 64 + r) * HDIM + (cb >> 1),
                  &kv_lds[buf][ch * 512]);
    }
  };
  auto stageV = [&](int buf, int jt) {
    #pragma unroll
    for (int it = 0; it < 4; ++it) {
      int ch = w * 4 + it;
      int r  = ch * 8 + (l >> 3);                            // V row (d) 0..127
      int cb = 16 * ((l & 7) ^ (l >> 3));                    // pre-swizzled col byte
      gload_lds16(vt + ((size_t)g * HDIM + r) * S_LEN + jt * 64 + (cb >> 1),
                  &kv_lds[buf][ch * 512]);
    }
  };

  f32x4 sc[5][4];
  #pragma unroll
  for (int t = 0; t < 5; ++t)
    #pragma unroll
    for (int jn = 0; jn < 4; ++jn) sc[t][jn] = (f32x4){0.f, 0.f, 0.f, 0.f};

  // ---- phase 1: QK^T with K prefetch ----
  stageK(0, jt0);
  __syncthreads();
  int buf = 0;
  #pragma unroll
  for (int t = 0; t < 5; ++t) {
    if (t < nt) {                                   // block-uniform
      if (t + 1 < nt) stageK(buf ^ 1, jt0 + t + 1);
      #pragma unroll
      for (int jn = 0; jn < 4; ++jn) {
        const int R = jn * 16 + lo16;
        #pragma unroll
        for (int kk = 0; kk < 4; ++kk) {
          int addr = R * 256 + ((kk * 64 + hi4 * 16) ^ ((R & 7) << 4));
          bf16x8 bk = *(const bf16x8*)((const char*)&kv_lds[buf][0] + addr);
          sc[t][jn] = __builtin_amdgcn_mfma_f32_16x16x32_bf16(aq[kk], bk, sc[t][jn], 0, 0, 0);
        }
      }
      __syncthreads();
      buf ^= 1;
    }
  }

  // ---- V[0] prefetch hides under softmax ----
  stageV(0, jt0);

  // ---- softmax: mask + scale + max, exp, P->LDS, sums (no barriers: per-wave P) ----
  float pmax[4] = {-3e38f, -3e38f, -3e38f, -3e38f};
  #pragma unroll
  for (int t = 0; t < 5; ++t) {
    if (t < nt) {
      const int jt = jt0 + t;
      const bool edge = (jt * 64 + 63 > rw) || (jt * 64 < rw - 240);
      #pragma unroll
      for (int jn = 0; jn < 4; ++jn) {
        const int jg = jt * 64 + jn * 16 + lo16;
        #pragma unroll
        for (int j = 0; j < 4; ++j) {
          float s2 = sc[t][jn][j] * scale;
          if (edge) {
            const int ig = rw + hi4 * 4 + j;
            bool valid = (jg <= ig) && (jg > ig - WINSZ);
            s2 = valid ? s2 : -1e30f;
          }
          sc[t][jn][j] = s2;
          pmax[j] = fmaxf(pmax[j], s2);
        }
      }
    }
  }
  #pragma unroll
  for (int off = 1; off < 16; off <<= 1)
    #pragma unroll
    for (int j = 0; j < 4; ++j) pmax[j] = fmaxf(pmax[j], __shfl_xor(pmax[j], off, 64));
  float m[4], rsum[4];
  #pragma unroll
  for (int j = 0; j < 4; ++j) { m[j] = fmaxf(pmax[j], sb); rsum[j] = 0.f; }

  #pragma unroll
  for (int t = 0; t < 5; ++t) {
    if (t < nt) {
      #pragma unroll
      for (int jn = 0; jn < 4; ++jn) {
        #pragma unroll
        for (int j = 0; j < 4; ++j) {
          float p = __expf(sc[t][jn][j] - m[j]);
          rsum[j] += p;
          int row = hi4 * 4 + j;
          int addr = (w * 5 + t) * 2048 + row * 128
                   + (((jn * 16 + lo16) * 2) ^ ((row & 7) << 4));
          *(u16*)((char*)p_lds + addr) = f2bf(p);
        }
      }
    }
  }
  #pragma unroll
  for (int off = 1; off < 16; off <<= 1)
    #pragma unroll
    for (int j = 0; j < 4; ++j) rsum[j] += __shfl_xor(rsum[j], off, 64);

  // ---- phase 2: PV with V prefetch ----
  f32x4 acc_o[8] = {};
  __syncthreads();   // V[0] staged + all waves past QK reads
  int vbuf = 0;
  #pragma unroll
  for (int t = 0; t < 5; ++t) {
    if (t < nt) {
      if (t + 1 < nt) stageV(vbuf ^ 1, jt0 + t + 1);
      #pragma unroll
      for (int kkp = 0; kkp < 2; ++kkp) {
        int pa = (w * 5 + t) * 2048 + lo16 * 128
               + ((kkp * 64 + hi4 * 16) ^ ((lo16 & 7) << 4));
        bf16x8 ap = *(const bf16x8*)((const char*)p_lds + pa);
        #pragma unroll
        for (int dn = 0; dn < 8; ++dn) {
          const int R = dn * 16 + lo16;
          int va = R * 128 + ((kkp * 64 + hi4 * 16) ^ ((R & 7) << 4));
          bf16x8 bv = *(const bf16x8*)((const char*)&kv_lds[vbuf][0] + va);
          acc_o[dn] = __builtin_amdgcn_mfma_f32_16x16x32_bf16(ap, bv, acc_o[dn], 0, 0, 0);
        }
      }
      __syncthreads();
      vbuf ^= 1;
    }
  }

  // ---- finalize ----
  float inv[4];
  #pragma unroll
  for (int j = 0; j < 4; ++j) inv[j] = 1.f / (rsum[j] + __expf(sb - m[j]));
  #pragma unroll
  for (int dn = 0; dn < 8; ++dn)
    #pragma unroll
    for (int j = 0; j < 4; ++j)
      ob[(size_t)(rw + hi4 * 4 + j) * DM + h * HDIM + dn * 16 + lo16] = f2bf(acc_o[dn][j] * inv[j]);
}

extern "C" void kernel_launch(void* const* d_in, const int* in_sizes, int n_in,
                              void* d_out, int out_size, void* d_ws, size_t ws_size,
                              hipStream_t stream) {
  const float* x  = (const float*)d_in[0];
  const float* sb = (const float*)d_in[1];
  const float* wq = (const float*)d_in[2];
  const float* bq = (const float*)d_in[3];
  const float* wk = (const float*)d_in[4];
  const float* bk = (const float*)d_in[5];
  const float* wv = (const float*)d_in[6];
  const float* bv = (const float*)d_in[7];
  const float* wo = (const float*)d_in[8];
  const float* bo = (const float*)d_in[9];
  float* out = (float*)d_out;
  char* ws = (char*)d_ws;

  u16* xb    = (u16*)(ws + OFF_XB);
  u16* wqkvb = (u16*)(ws + OFF_WQKV);
  u16* wob   = (u16*)(ws + OFF_WO);
  u16* qh    = (u16*)(ws + OFF_QH);
  u16* kh    = (u16*)(ws + OFF_KH);
  u16* vt    = (u16*)(ws + OFF_VT);
  u16* ob    = (u16*)(ws + OFF_OB);

  prep_kernel<<<dim3(6656), dim3(256), 0, stream>>>(x, wq, wk, wv, wo, xb, wqkvb, wob);
  gemm_bt<0><<<dim3(64, 12), dim3(256), 0, stream>>>(xb, wqkvb, bq, bk, bv, qh, kh, vt, nullptr);
  attn_kernel<<<dim3(64, 8), dim3(256), 0, stream>>>(qh, kh, vt, sb, ob);
  gemm_bt<1><<<dim3(64, 8), dim3(256), 0, stream>>>(ob, wob, bo, nullptr, nullptr,
                                                    nullptr, nullptr, nullptr, out);
}

// Round 5
// 77.193 us; speedup vs baseline: 1.4863x; 1.0617x over previous
//
#include <hip/hip_runtime.h>

#define S_LEN 4096
#define DM    1024
#define NH    8
#define NKV   2
#define HDIM  128
#define WINSZ 256

typedef unsigned short u16;
typedef float f32x4 __attribute__((ext_vector_type(4)));
typedef short bf16x8 __attribute__((ext_vector_type(8)));

// ---------- workspace layout (bytes) ----------
static const size_t OFF_XB   = 0;          // x bf16 [4096][1024]            8388608
static const size_t OFF_WQKV = 8388608;    // Wq|Wk|Wv bf16 [1536][1024]     3145728
static const size_t OFF_WO   = 11534336;   // Wo bf16 [1024][1024]           2097152
static const size_t OFF_QH   = 13631488;   // q bf16 [8][4096][128]          8388608
static const size_t OFF_KH   = 22020096;   // k bf16 [2][4096][128]          2097152
static const size_t OFF_VT   = 24117248;   // v^T bf16 [2][128][4096]        2097152
static const size_t OFF_OB   = 26214400;   // attn out bf16 [4096][1024]     8388608

__device__ __forceinline__ u16 f2bf(float f) {
  union { float f; unsigned int u; } v; v.f = f;
  unsigned int u = v.u;
  u += 0x7fffu + ((u >> 16) & 1u);   // RNE
  return (u16)(u >> 16);
}

__device__ __forceinline__ void gload_lds16(const u16* g, u16* l) {
  __builtin_amdgcn_global_load_lds((const __attribute__((address_space(1))) void*)g,
                                   (__attribute__((address_space(3))) void*)l, 16, 0, 0);
}

// ---------------- prep: f32 -> bf16 conversions ----------------
__global__ __launch_bounds__(256) void prep_kernel(
    const float* __restrict__ x,  const float* __restrict__ wq,
    const float* __restrict__ wk, const float* __restrict__ wv,
    const float* __restrict__ wo,
    u16* __restrict__ xb, u16* __restrict__ wqkvb, u16* __restrict__ wob) {
  int i = blockIdx.x * 256 + threadIdx.x;       // one float4 per thread
  const float* src; u16* dst;
  if (i < 1048576)      { src = x  + (size_t)i * 4;               dst = xb + (size_t)i * 4; }
  else if (i < 1310720) { int j = i - 1048576; src = wq + (size_t)j*4; dst = wqkvb + (size_t)j*4; }
  else if (i < 1376256) { int j = i - 1310720; src = wk + (size_t)j*4; dst = wqkvb + 1048576 + (size_t)j*4; }
  else if (i < 1441792) { int j = i - 1376256; src = wv + (size_t)j*4; dst = wqkvb + 1310720 + (size_t)j*4; }
  else                  { int j = i - 1441792; src = wo + (size_t)j*4; dst = wob + (size_t)j*4; }
  float4 v = *(const float4*)src;
  ushort4 o;
  o.x = f2bf(v.x); o.y = f2bf(v.y); o.z = f2bf(v.z); o.w = f2bf(v.w);
  *(ushort4*)dst = o;
}

// ---------------- GEMM: C[m][n] = sum_k A[m][k]*B[n][k]  (both K-major) ----------------
// 64x128 tile, BK=64, 4 waves (each 32x64 = 2x4 16x16x32 frags).
// Double-buffered LDS, STAGE(t+1) before compute(t). T2 XOR-swizzle (rule #21):
// global source col pre-swizzled 16*((l&7)^(l>>3)) bytes; reads XOR (row&7)<<4.
template<int EPI>
__global__ __launch_bounds__(256) void gemm_bt(
    const u16* __restrict__ A, const u16* __restrict__ B,
    const float* __restrict__ b0, const float* __restrict__ b1, const float* __restrict__ b2,
    u16* __restrict__ qh, u16* __restrict__ kh, u16* __restrict__ vt,
    float* __restrict__ outf) {
  __shared__ __align__(16) u16 As[2][64 * 64];     // 2 x 8 KB
  __shared__ __align__(16) u16 Bs[2][128 * 64];    // 2 x 16 KB
  const int tid = threadIdx.x;
  const int w = tid >> 6, l = tid & 63;
  const int lo16 = l & 15, hi4 = l >> 4;

  const int nwg = gridDim.x * gridDim.y;
  const int lin = blockIdx.y * gridDim.x + blockIdx.x;
  const int s = (lin & 7) * (nwg >> 3) + (lin >> 3);
  const int m0 = (s & 63) * 64;
  const int n0 = (s >> 6) * 128;

  const int wm = w >> 1, wn = w & 1;
  const int K = 1024;

  f32x4 acc[2][4] = {};

  const int lr = l >> 3;               // row within 8-row chunk
  const int sc8 = 8 * ((l & 7) ^ lr);  // pre-swizzled elem col within 64-wide row

  auto stage = [&](int buf, int kt) {
    #pragma unroll
    for (int it = 0; it < 6; ++it) {
      int c = w * 6 + it;                       // 24 chunks: 8 for As, 16 for Bs
      if (c < 8) {
        int row = c * 8 + lr;
        gload_lds16(A + (size_t)(m0 + row) * K + kt + sc8, &As[buf][c * 512]);
      } else {
        int cc = c - 8;
        int row = cc * 8 + lr;
        gload_lds16(B + (size_t)(n0 + row) * K + kt + sc8, &Bs[buf][cc * 512]);
      }
    }
  };

  stage(0, 0);
  __syncthreads();
  int buf = 0;
  const int rswz = (lo16 & 7) << 4;    // read-side XOR (row&7)<<4; rows = *+lo16
  for (int kt = 0; kt < K; kt += 64) {
    if (kt + 64 < K) stage(buf ^ 1, kt + 64);
    #pragma unroll
    for (int kk = 0; kk < 2; ++kk) {
      bf16x8 af[2], bfr[4];
      const int colb = (kk * 64 + hi4 * 16) ^ rswz;   // swizzled byte col in 128B row
      #pragma unroll
      for (int f = 0; f < 2; ++f)
        af[f] = *(const bf16x8*)((const char*)&As[buf][0] + (wm * 32 + f * 16 + lo16) * 128 + colb);
      #pragma unroll
      for (int fn = 0; fn < 4; ++fn)
        bfr[fn] = *(const bf16x8*)((const char*)&Bs[buf][0] + (wn * 64 + fn * 16 + lo16) * 128 + colb);
      #pragma unroll
      for (int fm = 0; fm < 2; ++fm)
        #pragma unroll
        for (int fn = 0; fn < 4; ++fn)
          acc[fm][fn] = __builtin_amdgcn_mfma_f32_16x16x32_bf16(af[fm], bfr[fn], acc[fm][fn], 0, 0, 0);
    }
    __syncthreads();   // drains prefetch vmcnt + protects buf reuse
    buf ^= 1;
  }

  #pragma unroll
  for (int fm = 0; fm < 2; ++fm) {
    #pragma unroll
    for (int fn = 0; fn < 4; ++fn) {
      f32x4 c = acc[fm][fn];
      const int col  = n0 + wn * 64 + fn * 16 + lo16;
      const int rowb = m0 + wm * 32 + fm * 16 + hi4 * 4;
      if (EPI == 0) {
        float bias = (col < 1024) ? b0[col] : (col < 1280 ? b1[col - 1024] : b2[col - 1280]);
        #pragma unroll
        for (int j = 0; j < 4; ++j) {
          int m = rowb + j;
          u16 hb = f2bf(c[j] + bias);
          if (col < 1024) {
            qh[((size_t)(col >> 7) * S_LEN + m) * HDIM + (col & 127)] = hb;
          } else if (col < 1280) {
            int cc = col - 1024;
            kh[((size_t)(cc >> 7) * S_LEN + m) * HDIM + (cc & 127)] = hb;
          } else {
            int cc = col - 1280;
            vt[((size_t)(cc >> 7) * HDIM + (cc & 127)) * S_LEN + m] = hb;
          }
        }
      } else {
        float bias = b0[col];
        #pragma unroll
        for (int j = 0; j < 4; ++j)
          outf[(size_t)(rowb + j) * DM + col] = c[j] + bias;
      }
    }
  }
}

// ---------------- attention: 4 waves / 64 q-rows, dbuf LDS-staged K/V ----------------
__global__ __launch_bounds__(256) void attn_kernel(
    const u16* __restrict__ qh, const u16* __restrict__ kh,
    const u16* __restrict__ vt, const float* __restrict__ sb_ptr,
    u16* __restrict__ ob) {
  __shared__ __align__(16) u16 kv_lds[2][8192];  // 2 x 16KB: K tile [64][256B] / V tile [128][128B]
  __shared__ __align__(16) u16 p_lds[20480];     // 40KB: wave w, tile t at (w*5+t)*2048 bytes
  const int r0 = blockIdx.x * 64;
  const int h  = blockIdx.y;
  const int g  = h >> 2;                 // H/KV = 4
  const int tid = threadIdx.x;
  const int w = tid >> 6, l = tid & 63;
  const int lo16 = l & 15, hi4 = l >> 4;
  const int rw = r0 + w * 16;
  const float sb = *sb_ptr;
  const float scale = 0.08838834764831845f;   // 1/sqrt(128)

  // Q fragments
  bf16x8 aq[4];
  {
    const u16* qbase = qh + ((size_t)h * S_LEN + rw + lo16) * HDIM + hi4 * 8;
    #pragma unroll
    for (int kk = 0; kk < 4; ++kk) aq[kk] = *(const bf16x8*)(qbase + kk * 32);
  }

  int lo = r0 - (WINSZ - 1); if (lo < 0) lo = 0;
  const int jt0 = lo >> 6;
  const int nt  = (r0 >> 6) - jt0 + 1;   // 1..5 (block-uniform)

  auto stageK = [&](int buf, int jt) {
    #pragma unroll
    for (int it = 0; it < 4; ++it) {
      int ch = w * 4 + it;
      int r  = ch * 4 + (l >> 4);                            // K row 0..63
      int cb = ((l & 15) * 16) ^ ((r & 7) << 4);             // pre-swizzled col byte
      gload_lds16(kh + ((size_t)g * S_LEN + jt * 64 + r) * HDIM + (cb >> 1),
                  &kv_lds[buf][ch * 512]);
    }
  };
  auto stageV = [&](int buf, int jt) {
    #pragma unroll
    for (int it = 0; it < 4; ++it) {
      int ch = w * 4 + it;
      int r  = ch * 8 + (l >> 3);                            // V row (d) 0..127
      int cb = 16 * ((l & 7) ^ (l >> 3));                    // pre-swizzled col byte
      gload_lds16(vt + ((size_t)g * HDIM + r) * S_LEN + jt * 64 + (cb >> 1),
                  &kv_lds[buf][ch * 512]);
    }
  };

  f32x4 sc[5][4];
  #pragma unroll
  for (int t = 0; t < 5; ++t)
    #pragma unroll
    for (int jn = 0; jn < 4; ++jn) sc[t][jn] = (f32x4){0.f, 0.f, 0.f, 0.f};

  // ---- phase 1: QK^T with K prefetch ----
  stageK(0, jt0);
  __syncthreads();
  int buf = 0;
  #pragma unroll
  for (int t = 0; t < 5; ++t) {
    if (t < nt) {                                   // block-uniform
      if (t + 1 < nt) stageK(buf ^ 1, jt0 + t + 1);
      #pragma unroll
      for (int jn = 0; jn < 4; ++jn) {
        const int R = jn * 16 + lo16;
        #pragma unroll
        for (int kk = 0; kk < 4; ++kk) {
          int addr = R * 256 + ((kk * 64 + hi4 * 16) ^ ((R & 7) << 4));
          bf16x8 bk = *(const bf16x8*)((const char*)&kv_lds[buf][0] + addr);
          sc[t][jn] = __builtin_amdgcn_mfma_f32_16x16x32_bf16(aq[kk], bk, sc[t][jn], 0, 0, 0);
        }
      }
      __syncthreads();
      buf ^= 1;
    }
  }

  // ---- V[0] prefetch hides under softmax ----
  stageV(0, jt0);

  // ---- softmax: mask + scale + max, exp, P->LDS, sums (no barriers: per-wave P) ----
  float pmax[4] = {-3e38f, -3e38f, -3e38f, -3e38f};
  #pragma unroll
  for (int t = 0; t < 5; ++t) {
    if (t < nt) {
      const int jt = jt0 + t;
      const bool edge = (jt * 64 + 63 > rw) || (jt * 64 < rw - 240);
      #pragma unroll
      for (int jn = 0; jn < 4; ++jn) {
        const int jg = jt * 64 + jn * 16 + lo16;
        #pragma unroll
        for (int j = 0; j < 4; ++j) {
          float s2 = sc[t][jn][j] * scale;
          if (edge) {
            const int ig = rw + hi4 * 4 + j;
            bool valid = (jg <= ig) && (jg > ig - WINSZ);
            s2 = valid ? s2 : -1e30f;
          }
          sc[t][jn][j] = s2;
          pmax[j] = fmaxf(pmax[j], s2);
        }
      }
    }
  }
  #pragma unroll
  for (int off = 1; off < 16; off <<= 1)
    #pragma unroll
    for (int j = 0; j < 4; ++j) pmax[j] = fmaxf(pmax[j], __shfl_xor(pmax[j], off, 64));
  float m[4], rsum[4];
  #pragma unroll
  for (int j = 0; j < 4; ++j) { m[j] = fmaxf(pmax[j], sb); rsum[j] = 0.f; }

  #pragma unroll
  for (int t = 0; t < 5; ++t) {
    if (t < nt) {
      #pragma unroll
      for (int jn = 0; jn < 4; ++jn) {
        #pragma unroll
        for (int j = 0; j < 4; ++j) {
          float p = __expf(sc[t][jn][j] - m[j]);
          rsum[j] += p;
          int row = hi4 * 4 + j;
          int addr = (w * 5 + t) * 2048 + row * 128
                   + (((jn * 16 + lo16) * 2) ^ ((row & 7) << 4));
          *(u16*)((char*)p_lds + addr) = f2bf(p);
        }
      }
    }
  }
  #pragma unroll
  for (int off = 1; off < 16; off <<= 1)
    #pragma unroll
    for (int j = 0; j < 4; ++j) rsum[j] += __shfl_xor(rsum[j], off, 64);

  // ---- phase 2: PV with V prefetch ----
  f32x4 acc_o[8] = {};
  __syncthreads();   // V[0] staged + all waves past QK reads
  int vbuf = 0;
  #pragma unroll
  for (int t = 0; t < 5; ++t) {
    if (t < nt) {
      if (t + 1 < nt) stageV(vbuf ^ 1, jt0 + t + 1);
      #pragma unroll
      for (int kkp = 0; kkp < 2; ++kkp) {
        int pa = (w * 5 + t) * 2048 + lo16 * 128
               + ((kkp * 64 + hi4 * 16) ^ ((lo16 & 7) << 4));
        bf16x8 ap = *(const bf16x8*)((const char*)p_lds + pa);
        #pragma unroll
        for (int dn = 0; dn < 8; ++dn) {
          const int R = dn * 16 + lo16;
          int va = R * 128 + ((kkp * 64 + hi4 * 16) ^ ((R & 7) << 4));
          bf16x8 bv = *(const bf16x8*)((const char*)&kv_lds[vbuf][0] + va);
          acc_o[dn] = __builtin_amdgcn_mfma_f32_16x16x32_bf16(ap, bv, acc_o[dn], 0, 0, 0);
        }
      }
      __syncthreads();
      vbuf ^= 1;
    }
  }

  // ---- finalize ----
  float inv[4];
  #pragma unroll
  for (int j = 0; j < 4; ++j) inv[j] = 1.f / (rsum[j] + __expf(sb - m[j]));
  #pragma unroll
  for (int dn = 0; dn < 8; ++dn)
    #pragma unroll
    for (int j = 0; j < 4; ++j)
      ob[(size_t)(rw + hi4 * 4 + j) * DM + h * HDIM + dn * 16 + lo16] = f2bf(acc_o[dn][j] * inv[j]);
}

extern "C" void kernel_launch(void* const* d_in, const int* in_sizes, int n_in,
                              void* d_out, int out_size, void* d_ws, size_t ws_size,
                              hipStream_t stream) {
  const float* x  = (const float*)d_in[0];
  const float* sb = (const float*)d_in[1];
  const float* wq = (const float*)d_in[2];
  const float* bq = (const float*)d_in[3];
  const float* wk = (const float*)d_in[4];
  const float* bk = (const float*)d_in[5];
  const float* wv = (const float*)d_in[6];
  const float* bv = (const float*)d_in[7];
  const float* wo = (const float*)d_in[8];
  const float* bo = (const float*)d_in[9];
  float* out = (float*)d_out;
  char* ws = (char*)d_ws;

  u16* xb    = (u16*)(ws + OFF_XB);
  u16* wqkvb = (u16*)(ws + OFF_WQKV);
  u16* wob   = (u16*)(ws + OFF_WO);
  u16* qh    = (u16*)(ws + OFF_QH);
  u16* kh    = (u16*)(ws + OFF_KH);
  u16* vt    = (u16*)(ws + OFF_VT);
  u16* ob    = (u16*)(ws + OFF_OB);

  prep_kernel<<<dim3(6656), dim3(256), 0, stream>>>(x, wq, wk, wv, wo, xb, wqkvb, wob);
  gemm_bt<0><<<dim3(64, 12), dim3(256), 0, stream>>>(xb, wqkvb, bq, bk, bv, qh, kh, vt, nullptr);
  attn_kernel<<<dim3(64, 8), dim3(256), 0, stream>>>(qh, kh, vt, sb, ob);
  gemm_bt<1><<<dim3(64, 8), dim3(256), 0, stream>>>(ob, wob, bo, nullptr, nullptr,
                                                    nullptr, nullptr, nullptr, out);
}